// Round 23
// baseline (134.894 us; speedup 1.0000x reference)
//
#include <hip/hip_runtime.h>
#include <stdint.h>
#include <math.h>

// Problem constants
#define BN 4096
#define TT 20
#define HH 256
#define EE 128
#define KK 5
#define NCOND 5

// ws layout (float indices)
#define WS_TSC  512                     // 20*1024 cumulative ts@Wk[384:404]
#define WS_WTB  20992                   // 80*256 bf16 u16, swizzled [n][k^((n&7)<<3)]
#define WS_BIAS 41472                   // 80 concat head biases (pad 0)
#define WS_ZC   42320                   // 1024   (be1@We2+be2)@Wk1 + bl
#define WS_M    43344                   // 5*1024 We1@We2@Wk1
#define WS_WSUM 48464                   // 256*1024 f32 Wk[128:384]+Wr (fallback path)
#define WS_WSB  310608                  // 1024*256 bf16 u16 LINEAR [col][k] (131072 u32)
#define WS_G    441680                  // gumbel [t][row][head][k]: 20*4096*4*5
#define WS_ZM   (WS_G + 4*TT*BN*KK)     // normals head0 [t][row][2]: 20*4096*2
#define WS_ZO   (WS_ZM + TT*BN*2)       // normals y/f/fa [t][row][3]: 20*4096*3
#define WS_END  (WS_ZO + 3*TT*BN)       // 2,489,680 floats = 9.96 MB

#define PSTR 84                         // psh row stride

#define TINYF 1.17549435e-38f
#define LO_N  0.99999994f               // -nextafter(-1,0)
#define LOG2E 1.44269504f
#define LN2   0.69314718f

typedef __attribute__((ext_vector_type(8))) short short8v;   // 8 bf16 (4 VGPRs)
typedef __attribute__((ext_vector_type(4))) float f32x4;     // 4 fp32 acc

// ---------------- Threefry-2x32 (JAX-exact) ----------------
__device__ __host__ __forceinline__ constexpr void tf2(
    uint32_t k0, uint32_t k1, uint32_t x0, uint32_t x1, uint32_t& o0, uint32_t& o1) {
  const uint32_t ks2 = k0 ^ k1 ^ 0x1BD11BDAu;
  x0 += k0; x1 += k1;
#define RND(r) { x0 += x1; x1 = (x1 << (r)) | (x1 >> (32 - (r))); x1 ^= x0; }
  RND(13) RND(15) RND(26) RND(6)   x0 += k1;  x1 += ks2 + 1u;
  RND(17) RND(29) RND(16) RND(24)  x0 += ks2; x1 += k0 + 2u;
  RND(13) RND(15) RND(26) RND(6)   x0 += k0;  x1 += k1 + 3u;
  RND(17) RND(29) RND(16) RND(24)  x0 += k1;  x1 += ks2 + 4u;
  RND(13) RND(15) RND(26) RND(6)   x0 += ks2; x1 += k0 + 5u;
#undef RND
  o0 = x0; o1 = x1;
}

// compile-time key table: per step t, 4 heads x (k1.x,k1.y,k2.x,k2.y)
struct KeyTab { uint32_t v[TT * 16]; };
constexpr KeyTab mkkeys() {
  KeyTab kt{};
  uint32_t kx = 0u, ky = 42u;   // jax.random.key(42)
  for (int t = 0; t < TT; ++t) {
    for (int l = 0; l < 4; ++l) {
      uint32_t hx = 0, hy = 0, a = 0, b = 0, c = 0, d = 0;
      tf2(kx, ky, 0u, (uint32_t)(l + 1), hx, hy);
      tf2(hx, hy, 0u, 0u, a, b);
      tf2(hx, hy, 0u, 1u, c, d);
      kt.v[t * 16 + l * 4 + 0] = a;
      kt.v[t * 16 + l * 4 + 1] = b;
      kt.v[t * 16 + l * 4 + 2] = c;
      kt.v[t * 16 + l * 4 + 3] = d;
    }
    uint32_t nx = 0, ny = 0;
    tf2(kx, ky, 0u, 0u, nx, ny);
    kx = nx; ky = ny;
  }
  return kt;
}
__constant__ KeyTab KT = mkkeys();

// jax_threefry_partitionable: bits[n] = a ^ b, (a,b) = threefry2x32(key, (0, n))
__device__ __forceinline__ uint32_t pbits(uint32_t k0, uint32_t k1, uint32_t n) {
  uint32_t a, b;
  tf2(k0, k1, 0u, n, a, b);
  return a ^ b;
}

__device__ __forceinline__ float u01f(uint32_t bits) {
  return __uint_as_float((bits >> 9) | 0x3f800000u) - 1.0f;
}

// ---- hardware transcendentals ----
__device__ __forceinline__ float fexp(float x) { return __builtin_amdgcn_exp2f(x * LOG2E); }
__device__ __forceinline__ float flog(float x) { return __builtin_amdgcn_logf(x) * LN2; }
__device__ __forceinline__ float frcp(float x) { return __builtin_amdgcn_rcpf(x); }
__device__ __forceinline__ float fsig(float x) {
  return frcp(1.0f + __builtin_amdgcn_exp2f(-x * LOG2E));
}
__device__ __forceinline__ float ftanh(float x) {
  return 1.0f - 2.0f * frcp(1.0f + __builtin_amdgcn_exp2f(x * (2.0f * LOG2E)));
}

// XLA ErfInv32 (Giles polynomial), log via hw
__device__ __forceinline__ float erfinv_f(float x) {
  float w = -flog(fmaf(-x, x, 1.0f));
  float p;
  if (w < 5.0f) {
    w = w - 2.5f;
    p = 2.81022636e-08f;
    p = 3.43273939e-07f + p * w;
    p = -3.5233877e-06f + p * w;
    p = -4.39150654e-06f + p * w;
    p = 0.00021858087f  + p * w;
    p = -0.00125372503f + p * w;
    p = -0.00417768164f + p * w;
    p = 0.246640727f    + p * w;
    p = 1.50140941f     + p * w;
  } else {
    w = sqrtf(w) - 3.0f;
    p = -0.000200214257f;
    p = 0.000100950558f + p * w;
    p = 0.00134934322f  + p * w;
    p = -0.00367342844f + p * w;
    p = 0.00573950773f  + p * w;
    p = -0.0076224613f  + p * w;
    p = 0.00943887047f  + p * w;
    p = 1.00167406f     + p * w;
    p = 2.83297682f     + p * w;
  }
  return p * x;
}

// round-to-nearest-even f32 -> bf16 bits
__device__ __forceinline__ uint32_t bf16rne(float f) {
  uint32_t u = __float_as_uint(f);
  return (u + 0x7fffu + ((u >> 16) & 1u)) >> 16;
}

// ======== prep_misc: register-LIGHT 256-thread blocks, ALL self-contained ========
// [0,8000)           RNG G/ZM/ZO (2,048,000 = 8000x256; time-major layouts)
// [8000,9024)        WSUM f32 (decode fallback)
// [9024,10048)       WSB bf16 [col][k] (from Wk+Wr directly)
// [10048,10052)      tsc cumulative
// [10052,10132)      WTB bf16 swizzled
// [10132]            bias
// [10133,10137)      M + zc-global (T1/eb2 local)
#define RB_RNG   0
#define RB_WSUM  8000
#define RB_WSB   9024
#define RB_TSC   10048
#define RB_WTB   10052
#define RB_BIAS  10132
#define RB_MZC   10133
#define RB_TOT   10137
__global__ __launch_bounds__(256) void prep_misc(
    const float* __restrict__ Wk, const float* __restrict__ Wr,
    const float* __restrict__ We1, const float* __restrict__ be1,
    const float* __restrict__ We2, const float* __restrict__ be2,
    const float* __restrict__ Wm, const float* __restrict__ bm,
    const float* __restrict__ Wy, const float* __restrict__ by,
    const float* __restrict__ Wf, const float* __restrict__ bf,
    const float* __restrict__ Wfa, const float* __restrict__ bfa,
    const float* __restrict__ bl, float* __restrict__ ws) {
  __shared__ float smem[768];           // MZC: T1(640)+eb2(128)
  const int bid = blockIdx.x, tid = threadIdx.x;

  if (bid < RB_WSUM) {
    const int id = bid * 256 + tid;
    const int NG = 4 * TT * BN * KK;
    if (id < NG) {
      // layout [t][row][head][k]; value = gumbel(key(head,t), n=row*5+k)
      const int t = id / (BN * 4 * KK);
      const int r1 = id % (BN * 4 * KK);
      const int row = r1 / (4 * KK);
      const int r2 = r1 % (4 * KK);
      const int head = r2 / KK, k = r2 % KK;
      const uint32_t k0 = KT.v[t * 16 + head * 4 + 0], k1 = KT.v[t * 16 + head * 4 + 1];
      float u = u01f(pbits(k0, k1, (uint32_t)(row * KK + k)));
      u = fmaxf(TINYF, u * (1.0f - TINYF) + TINYF);
      ws[WS_G + id] = -flog(-flog(u));
    } else if (id < NG + TT * BN * 2) {
      const int jj = id - NG;
      const int t = jj / (BN * 2);
      const uint32_t n = (uint32_t)(jj % (BN * 2));
      const uint32_t k0 = KT.v[t * 16 + 2], k1 = KT.v[t * 16 + 3];
      float u = u01f(pbits(k0, k1, n)) * 2.0f - LO_N;
      u = fmaxf(-LO_N, u);
      ws[WS_ZM + jj] = 1.41421356f * erfinv_f(u);
    } else {
      // layout [t][row][3]; value = normal(key2(head hh+1,t), n=row)
      const int jj = id - NG - TT * BN * 2;
      const int t = jj / (BN * 3);
      const int r2 = jj % (BN * 3);
      const int row = r2 / 3, hh = r2 % 3;
      const uint32_t k0 = KT.v[t * 16 + (hh + 1) * 4 + 2];
      const uint32_t k1 = KT.v[t * 16 + (hh + 1) * 4 + 3];
      float u = u01f(pbits(k0, k1, (uint32_t)row)) * 2.0f - LO_N;
      u = fmaxf(-LO_N, u);
      ws[WS_ZO + jj] = 1.41421356f * erfinv_f(u);
    }
  } else if (bid < RB_WSB) {
    const int idx = (bid - RB_WSUM) * 256 + tid;    // < 262144
    const int q = idx >> 10, col = idx & 1023;
    ws[WS_WSUM + idx] = Wk[(size_t)(EE + q) * 1024 + col] + Wr[(size_t)q * 1024 + col];
  } else if (bid < RB_TSC) {
    // WSB[col][q] bf16 (self-contained from Wk+Wr); coalesced u16 writes
    const int col = bid - RB_WSB;
    const int q = tid;
    uint16_t* wsb = (uint16_t*)&ws[WS_WSB];
    wsb[col * 256 + q] =
        (uint16_t)bf16rne(Wk[(size_t)(EE + q) * 1024 + col] + Wr[(size_t)q * 1024 + col]);
  } else if (bid < RB_WTB) {
    const int col = (bid - RB_TSC) * 256 + tid;
    float s = 0.0f;
    for (int p = 0; p < TT; ++p) {
      s += Wk[(size_t)(EE + HH + p) * 1024 + col];
      ws[WS_TSC + p * 1024 + col] = s;
    }
  } else if (bid < RB_BIAS) {
    const int idx = (bid - RB_WTB) * 256 + tid;   // < 20480
    const int o = idx >> 8, q = idx & 255;
    float v = 0.0f;
    if (o < 30)      v = Wm[q * 30 + o];
    else if (o < 45) v = Wy[q * 15 + (o - 30)];
    else if (o < 60) v = Wf[q * 15 + (o - 45)];
    else if (o < 75) v = Wfa[q * 15 + (o - 60)];
    uint16_t* wtb = (uint16_t*)&ws[WS_WTB];
    wtb[o * 256 + (q ^ ((o & 7) << 3))] = (uint16_t)bf16rne(v);
  } else if (bid == RB_BIAS) {
    if (tid < 80) {
      float v = 0.0f;
      if (tid < 30)      v = bm[tid];
      else if (tid < 45) v = by[tid - 30];
      else if (tid < 60) v = bf[tid - 45];
      else if (tid < 75) v = bfa[tid - 60];
      ws[WS_BIAS + tid] = v;
    }
  } else {
    // M = (We1@We2)@Wk1; zc-global = (be1@We2+be2)@Wk1 + bl (T1/eb2 local)
    float* T1s = smem;                // 5*128
    float* eb2s = smem + 640;         // 128
    if (tid < EE) {
      const int q = tid;
      float t0 = 0.f, t1 = 0.f, t2 = 0.f, t3 = 0.f, t4 = 0.f;
      float eb = be2[q];
      for (int e = 0; e < EE; ++e) {
        const float w2 = We2[e * EE + q];
        t0 = fmaf(We1[0 * EE + e], w2, t0);
        t1 = fmaf(We1[1 * EE + e], w2, t1);
        t2 = fmaf(We1[2 * EE + e], w2, t2);
        t3 = fmaf(We1[3 * EE + e], w2, t3);
        t4 = fmaf(We1[4 * EE + e], w2, t4);
        eb = fmaf(be1[e], w2, eb);
      }
      T1s[0 * 128 + q] = t0; T1s[1 * 128 + q] = t1; T1s[2 * 128 + q] = t2;
      T1s[3 * 128 + q] = t3; T1s[4 * 128 + q] = t4; eb2s[q] = eb;
    }
    __syncthreads();
    const int col = (bid - RB_MZC) * 256 + tid;   // 0..1023
    float m0 = 0.f, m1 = 0.f, m2 = 0.f, m3 = 0.f, m4 = 0.f;
    float zacc = bl[col];
    for (int q = 0; q < EE; ++q) {
      const float wv = Wk[(size_t)q * 1024 + col];
      m0 = fmaf(T1s[0 * 128 + q], wv, m0);
      m1 = fmaf(T1s[1 * 128 + q], wv, m1);
      m2 = fmaf(T1s[2 * 128 + q], wv, m2);
      m3 = fmaf(T1s[3 * 128 + q], wv, m3);
      m4 = fmaf(T1s[4 * 128 + q], wv, m4);
      zacc = fmaf(eb2s[q], wv, zacc);
    }
    ws[WS_M + 0 * 1024 + col] = m0;
    ws[WS_M + 1 * 1024 + col] = m1;
    ws[WS_M + 2 * 1024 + col] = m2;
    ws[WS_M + 3 * 1024 + col] = m3;
    ws[WS_M + 4 * 1024 + col] = m4;
    ws[WS_ZC + col] = zacc;
  }
}

// ---- main: 8 rows/block, 512 blocks, 20 steps; cz via in-prologue MFMA ----
__global__ __launch_bounds__(512) void decode_main(
    const float* __restrict__ conditions, const float* __restrict__ state_h,
    const float* __restrict__ state_c, const float* __restrict__ ws,
    float* __restrict__ out, int use_cz) {
  __shared__ float Msh[5 * 1024];       // 20 KB
  __shared__ short WTBs[80 * 256];      // 40 KB weights; prologue: 32 KB czs scratch
  __shared__ short hb[16 * 256];        // 8 KB bf16 swizzled h (rows 8..15 zero)
  __shared__ float psh[8 * PSTR];       // head outputs (pre-biased)
  __shared__ float biasL[80];
  __shared__ float conds[8 * 8];

  const int tid = threadIdx.x;
  const int row0 = blockIdx.x * 8;
  const int u = tid & 255;
  const int half = tid >> 8;
  const int rbase = half * 4;

  for (int i = tid; i < 5 * 1024; i += 512) Msh[i] = ws[WS_M + i];
  if (tid < 80) biasL[tid] = ws[WS_BIAS + tid];
  if (tid < 8 * NCOND) {
    const int r = tid / NCOND, c = tid - r * NCOND;
    conds[r * 8 + c] = conditions[(size_t)(row0 + r) * (TT * NCOND) + c];  // [:,0,:]
  }
  float sc[4];
#pragma unroll
  for (int rr = 0; rr < 4; ++rr) sc[rr] = state_c[(size_t)(row0 + rbase + rr) * HH + u];

  // Phase-C role constants (t-invariant)
  const bool cth = (tid < 256);
  const int kci = tid & 7;
  const int rci = tid >> 5;
  const int headci = (tid >> 3) & 3;
  const int crow = row0 + rci;
  const int cbase2 = headci ? (30 + 15 * (headci - 1)) : 0;

  float cz[4][4];
  if (use_cz) {
    // ---- stage A: hb = bf16(state_h rows, swizzled); pads zero ----
    {
      uint32_t* hz = (uint32_t*)hb;
      for (int i = tid; i < 1024; i += 512) hz[1024 + i] = 0u;   // rows 8..15 ONLY
      for (int i = tid; i < 8 * HH; i += 512) {
        const int m = i >> 8, k = i & 255;
        hb[m * 256 + (k ^ ((m & 7) << 3))] =
            (short)bf16rne(state_h[(size_t)(row0 + m) * HH + k]);
      }
    }
    __syncthreads();
    // ---- MFMA: czs[8][1024] = hb @ WSB^T + zc (bit-identical to czgemm) ----
    {
      float* czs = (float*)WTBs;        // 32 KB scratch over WTBs region
      const short* wsb = (const short*)&ws[WS_WSB];
      const int wv = tid >> 6, lane = tid & 63;
      const int rc = lane & 15, hq = lane >> 4;
      const int aswz = (rc & 7) << 3;
      short8v av[8];
#pragma unroll
      for (int kk = 0; kk < 8; ++kk)
        av[kk] = *(const short8v*)&hb[rc * 256 + ((kk * 32 + hq * 8) ^ aswz)];
#pragma unroll
      for (int i = 0; i < 8; ++i) {
        const int nn = (wv * 8 + i) * 16 + rc;   // output col 0..1023
        f32x4 acc = {0.f, 0.f, 0.f, 0.f};
#pragma unroll
        for (int kk = 0; kk < 8; ++kk) {
          const short8v bv = *(const short8v*)&wsb[nn * 256 + kk * 32 + hq * 8];
          acc = __builtin_amdgcn_mfma_f32_16x16x32_bf16(av[kk], bv, acc, 0, 0, 0);
        }
        if (hq < 2) {
          const float zcv = ws[WS_ZC + nn];
#pragma unroll
          for (int j = 0; j < 4; ++j)
            czs[(hq * 4 + j) * 1024 + nn] = acc[j] + zcv;
        }
      }
    }
    __syncthreads();
#pragma unroll
    for (int g = 0; g < 4; ++g)
#pragma unroll
      for (int rr = 0; rr < 4; ++rr)
        cz[g][rr] = ((float*)WTBs)[(rbase + rr) * 1024 + g * 256 + u];
    __syncthreads();   // all czs reads done before WTBs overwrite
    {
      uint32_t* dst = (uint32_t*)WTBs;
      const uint32_t* src = (const uint32_t*)&ws[WS_WTB];
      for (int i = tid; i < 80 * 128; i += 512) dst[i] = src[i];
    }
    __syncthreads();
  } else {
    float* hstage = (float*)WTBs;
    for (int i = tid; i < 8 * HH; i += 512) hstage[i] = state_h[(size_t)row0 * HH + i];
    __syncthreads();
#pragma unroll
    for (int g = 0; g < 4; ++g) {
      const float z = ws[WS_ZC + g * 256 + u];
#pragma unroll
      for (int rr = 0; rr < 4; ++rr) cz[g][rr] = z;
    }
    for (int q = 0; q < HH; ++q) {
      const float w0 = ws[WS_WSUM + q * 1024 + u];
      const float w1 = ws[WS_WSUM + q * 1024 + 256 + u];
      const float w2 = ws[WS_WSUM + q * 1024 + 512 + u];
      const float w3 = ws[WS_WSUM + q * 1024 + 768 + u];
#pragma unroll
      for (int rr = 0; rr < 4; ++rr) {
        const float e = hstage[(rbase + rr) * HH + q];
        cz[0][rr] = fmaf(e, w0, cz[0][rr]);
        cz[1][rr] = fmaf(e, w1, cz[1][rr]);
        cz[2][rr] = fmaf(e, w2, cz[2][rr]);
        cz[3][rr] = fmaf(e, w3, cz[3][rr]);
      }
    }
    __syncthreads();
    {
      uint32_t* dst = (uint32_t*)WTBs;
      const uint32_t* src = (const uint32_t*)&ws[WS_WTB];
      for (int i = tid; i < 80 * 128; i += 512) dst[i] = src[i];
      uint32_t* hz = (uint32_t*)hb;
      for (int i = tid; i < 1024; i += 512) hz[1024 + i] = 0u;
    }
    __syncthreads();
  }

  for (int t = 0; t < TT; ++t) {
    // ---- prefetch step-t RNG draws into registers (hides cold-HBM under A/B) ----
    float pg = 0.0f, pz0 = 0.0f, pz1 = 0.0f, pzz = 0.0f;
    if (cth) {
      if (kci < 5)
        pg = ws[WS_G + (((size_t)t * BN + crow) * 4 + headci) * KK + kci];
      if (kci == 0) {
        if (headci == 0) {
          pz0 = ws[WS_ZM + ((size_t)t * BN + crow) * 2 + 0];
          pz1 = ws[WS_ZM + ((size_t)t * BN + crow) * 2 + 1];
        } else {
          pzz = ws[WS_ZO + ((size_t)t * BN + crow) * 3 + (headci - 1)];
        }
      }
    }
    // ---- Phase A ----
    {
      const float ts0 = ws[WS_TSC + t * 1024 + u];
      const float ts1 = ws[WS_TSC + t * 1024 + 256 + u];
      const float ts2 = ws[WS_TSC + t * 1024 + 512 + u];
      const float ts3 = ws[WS_TSC + t * 1024 + 768 + u];
      float mA[5], mB[5], mC[5], mD[5];
#pragma unroll
      for (int c = 0; c < 5; ++c) {
        mA[c] = Msh[c * 1024 + u];
        mB[c] = Msh[c * 1024 + 256 + u];
        mC[c] = Msh[c * 1024 + 512 + u];
        mD[c] = Msh[c * 1024 + 768 + u];
      }
#pragma unroll
      for (int rr = 0; rr < 4; ++rr) {
        const int row = rbase + rr;
        const float c0 = conds[row * 8 + 0], c1 = conds[row * 8 + 1], c2 = conds[row * 8 + 2],
                    c3 = conds[row * 8 + 3], c4 = conds[row * 8 + 4];
        float zi = cz[0][rr] + ts0, zf = cz[1][rr] + ts1,
              zg = cz[2][rr] + ts2, zo = cz[3][rr] + ts3;
        zi = fmaf(c0, mA[0], zi); zi = fmaf(c1, mA[1], zi); zi = fmaf(c2, mA[2], zi);
        zi = fmaf(c3, mA[3], zi); zi = fmaf(c4, mA[4], zi);
        zf = fmaf(c0, mB[0], zf); zf = fmaf(c1, mB[1], zf); zf = fmaf(c2, mB[2], zf);
        zf = fmaf(c3, mB[3], zf); zf = fmaf(c4, mB[4], zf);
        zg = fmaf(c0, mC[0], zg); zg = fmaf(c1, mC[1], zg); zg = fmaf(c2, mC[2], zg);
        zg = fmaf(c3, mC[3], zg); zg = fmaf(c4, mC[4], zg);
        zo = fmaf(c0, mD[0], zo); zo = fmaf(c1, mD[1], zo); zo = fmaf(c2, mD[2], zo);
        zo = fmaf(c3, mD[3], zo); zo = fmaf(c4, mD[4], zo);
        const float cv = fsig(zf) * sc[rr] + fsig(zi) * ftanh(zg);
        const float hv = fsig(zo) * ftanh(cv);
        hb[row * 256 + (u ^ ((row & 7) << 3))] = (short)bf16rne(hv);
      }
    }
    __syncthreads();
    // ---- Phase B: MFMA heads ----
    {
      const int wv = tid >> 6;
      if (wv < 5) {
        const int lane = tid & 63;
        const int rc = lane & 15;
        const int hq = lane >> 4;
        const int nn = wv * 16 + rc;
        const int aswz = (rc & 7) << 3;
        const int bswz = (nn & 7) << 3;
        f32x4 acc = {0.0f, 0.0f, 0.0f, 0.0f};
#pragma unroll
        for (int kk = 0; kk < 8; ++kk) {
          const int kbase = kk * 32 + hq * 8;
          const short8v av = *(const short8v*)&hb[rc * 256 + (kbase ^ aswz)];
          const short8v bv = *(const short8v*)&WTBs[nn * 256 + (kbase ^ bswz)];
          acc = __builtin_amdgcn_mfma_f32_16x16x32_bf16(av, bv, acc, 0, 0, 0);
        }
        if (hq < 2) {
#pragma unroll
          for (int j = 0; j < 4; ++j) {
            const int prow = hq * 4 + j;
            psh[prow * PSTR + nn] = acc[j] + biasL[nn];
          }
        }
      }
    }
    __syncthreads();
    // ---- Phase C: wave-parallel sampling (prefetched RNG) ----
    if (cth) {
      const float lk = (kci < 5) ? psh[rci * PSTR + cbase2 + kci] : -INFINITY;
      float mx = fmaxf(lk, __shfl_xor(lk, 1));
      mx = fmaxf(mx, __shfl_xor(mx, 2));
      mx = fmaxf(mx, __shfl_xor(mx, 4));
      const float ek = (kci < 5) ? fexp(lk - mx) : 0.0f;
      float ss = ek + __shfl_xor(ek, 1);
      ss += __shfl_xor(ss, 2);
      ss += __shfl_xor(ss, 4);
      const float rss = frcp(ss);
      float v = -INFINITY;
      if (kci < 5) v = lk + pg;
      float vm = fmaxf(v, __shfl_xor(v, 1));
      vm = fmaxf(vm, __shfl_xor(vm, 2));
      vm = fmaxf(vm, __shfl_xor(vm, 4));
      int cand = (v == vm) ? kci : 8;
      cand = min(cand, __shfl_xor(cand, 1));
      cand = min(cand, __shfl_xor(cand, 2));
      cand = min(cand, __shfl_xor(cand, 4));
      const int idx = cand;
      const size_t ob = headci
          ? ((size_t)BN * TT * 30 + (size_t)(headci - 1) * BN * TT * 15 +
             ((size_t)crow * TT + t) * 15)
          : ((size_t)crow * TT + t) * 30;
      if (kci < 5) {
        out[ob + kci] = ek * rss;
        out[ob + 5 + kci] = psh[rci * PSTR + cbase2 + 5 + kci];
        out[ob + 10 + kci] = fexp(psh[rci * PSTR + cbase2 + 10 + kci]);
        if (headci == 0) {
          out[ob + 15 + kci] = psh[rci * PSTR + 15 + kci];
          out[ob + 20 + kci] = fexp(psh[rci * PSTR + 20 + kci]);
          out[ob + 25 + kci] = ftanh(psh[rci * PSTR + 25 + kci]);
        }
      }
      if (kci == 0) {
        if (headci == 0) {
          const float mu = psh[rci * PSTR + 5 + idx];
          const float sl = fexp(psh[rci * PSTR + 10 + idx]);
          const float mula = psh[rci * PSTR + 15 + idx];
          const float sla = fexp(psh[rci * PSTR + 20 + idx]);
          const float rho = ftanh(psh[rci * PSTR + 25 + idx]);
          conds[rci * 8 + 0] = mu + sl * pz0;
          conds[rci * 8 + 1] = mula + sla * (rho * pz0 + sqrtf(1.0f - rho * rho) * pz1);
        } else {
          conds[rci * 8 + 1 + headci] =
              psh[rci * PSTR + cbase2 + 5 + idx] +
              fexp(psh[rci * PSTR + cbase2 + 10 + idx]) * pzz;
        }
      }
    }
    __syncthreads();
  }
}

extern "C" void kernel_launch(void* const* d_in, const int* in_sizes, int n_in,
                              void* d_out, int out_size, void* d_ws, size_t ws_size,
                              hipStream_t stream) {
  const float* conditions = (const float*)d_in[0];
  const float* state_h = (const float*)d_in[1];
  const float* state_c = (const float*)d_in[2];
  // d_in[3] = steps_n (=20, compile-time TT)
  const float* We1 = (const float*)d_in[4];
  const float* be1 = (const float*)d_in[5];
  const float* We2 = (const float*)d_in[6];
  const float* be2 = (const float*)d_in[7];
  const float* Wk  = (const float*)d_in[8];
  const float* Wr  = (const float*)d_in[9];
  const float* bl  = (const float*)d_in[10];
  const float* Wm  = (const float*)d_in[11];
  const float* bm  = (const float*)d_in[12];
  const float* Wy  = (const float*)d_in[13];
  const float* by  = (const float*)d_in[14];
  const float* Wf  = (const float*)d_in[15];
  const float* bf  = (const float*)d_in[16];
  const float* Wfa = (const float*)d_in[17];
  const float* bfa = (const float*)d_in[18];
  float* ws = (float*)d_ws;
  float* out = (float*)d_out;

  const int use_cz = (ws_size >= (size_t)WS_END * 4) ? 1 : 0;

  prep_misc<<<dim3(RB_TOT), dim3(256), 0, stream>>>(
      Wk, Wr, We1, be1, We2, be2, Wm, bm, Wy, by, Wf, bf, Wfa, bfa, bl, ws);
  decode_main<<<dim3(BN / 8), dim3(512), 0, stream>>>(
      conditions, state_h, state_c, ws, out, use_cz);
}

// Round 24
// 118.801 us; speedup vs baseline: 1.1355x; 1.1355x over previous
//
#include <hip/hip_runtime.h>
#include <stdint.h>
#include <math.h>

// Problem constants
#define BN 4096
#define TT 20
#define HH 256
#define EE 128
#define KK 5
#define NCOND 5

// ws layout (float indices)
#define WS_TSC  512                     // 20*1024 cumulative ts@Wk[384:404]
#define WS_WTB  20992                   // 80*256 bf16 u16, swizzled [n][k^((n&7)<<3)]
#define WS_BIAS 41472                   // 80 concat head biases (pad 0)
#define WS_ZC   42320                   // 1024   (be1@We2+be2)@Wk1 + bl
#define WS_M    43344                   // 5*1024 We1@We2@Wk1
#define WS_WSUM 48464                   // 256*1024  Wk[128:384] + Wr
#define WS_G    310608                  // gumbel [t][row][head][k]: 20*4096*4*5 (16B-aligned)
#define WS_ZM   (WS_G + 4*TT*BN*KK)     // normals head0 [t][row][2]: 20*4096*2
#define WS_ZO   (WS_ZM + TT*BN*2)       // normals y/f/fa [t][row][3]: 20*4096*3
#define WS_CZ   (WS_ZO + 3*TT*BN)       // cz_all [4096][1024] f32
#define WS_END  (WS_CZ + BN*1024)       // 6,552,912 floats = 26.2 MB

#define PSTR 84                         // psh row stride

#define TINYF 1.17549435e-38f
#define LO_N  0.99999994f               // -nextafter(-1,0)
#define LOG2E 1.44269504f
#define LN2   0.69314718f

typedef __attribute__((ext_vector_type(8))) short short8v;   // 8 bf16 (4 VGPRs)
typedef __attribute__((ext_vector_type(4))) float f32x4;     // 4 fp32 acc

// ---------------- Threefry-2x32 (JAX-exact) ----------------
__device__ __host__ __forceinline__ constexpr void tf2(
    uint32_t k0, uint32_t k1, uint32_t x0, uint32_t x1, uint32_t& o0, uint32_t& o1) {
  const uint32_t ks2 = k0 ^ k1 ^ 0x1BD11BDAu;
  x0 += k0; x1 += k1;
#define RND(r) { x0 += x1; x1 = (x1 << (r)) | (x1 >> (32 - (r))); x1 ^= x0; }
  RND(13) RND(15) RND(26) RND(6)   x0 += k1;  x1 += ks2 + 1u;
  RND(17) RND(29) RND(16) RND(24)  x0 += ks2; x1 += k0 + 2u;
  RND(13) RND(15) RND(26) RND(6)   x0 += k0;  x1 += k1 + 3u;
  RND(17) RND(29) RND(16) RND(24)  x0 += k1;  x1 += ks2 + 4u;
  RND(13) RND(15) RND(26) RND(6)   x0 += ks2; x1 += k0 + 5u;
#undef RND
  o0 = x0; o1 = x1;
}

// compile-time key table: per step t, 4 heads x (k1.x,k1.y,k2.x,k2.y)
struct KeyTab { uint32_t v[TT * 16]; };
constexpr KeyTab mkkeys() {
  KeyTab kt{};
  uint32_t kx = 0u, ky = 42u;   // jax.random.key(42)
  for (int t = 0; t < TT; ++t) {
    for (int l = 0; l < 4; ++l) {
      uint32_t hx = 0, hy = 0, a = 0, b = 0, c = 0, d = 0;
      tf2(kx, ky, 0u, (uint32_t)(l + 1), hx, hy);
      tf2(hx, hy, 0u, 0u, a, b);
      tf2(hx, hy, 0u, 1u, c, d);
      kt.v[t * 16 + l * 4 + 0] = a;
      kt.v[t * 16 + l * 4 + 1] = b;
      kt.v[t * 16 + l * 4 + 2] = c;
      kt.v[t * 16 + l * 4 + 3] = d;
    }
    uint32_t nx = 0, ny = 0;
    tf2(kx, ky, 0u, 0u, nx, ny);
    kx = nx; ky = ny;
  }
  return kt;
}
__constant__ KeyTab KT = mkkeys();

// jax_threefry_partitionable: bits[n] = a ^ b, (a,b) = threefry2x32(key, (0, n))
__device__ __forceinline__ uint32_t pbits(uint32_t k0, uint32_t k1, uint32_t n) {
  uint32_t a, b;
  tf2(k0, k1, 0u, n, a, b);
  return a ^ b;
}

__device__ __forceinline__ float u01f(uint32_t bits) {
  return __uint_as_float((bits >> 9) | 0x3f800000u) - 1.0f;
}

// ---- hardware transcendentals ----
__device__ __forceinline__ float fexp(float x) { return __builtin_amdgcn_exp2f(x * LOG2E); }
__device__ __forceinline__ float flog(float x) { return __builtin_amdgcn_logf(x) * LN2; }
__device__ __forceinline__ float frcp(float x) { return __builtin_amdgcn_rcpf(x); }
__device__ __forceinline__ float fsig(float x) {
  return frcp(1.0f + __builtin_amdgcn_exp2f(-x * LOG2E));
}
__device__ __forceinline__ float ftanh(float x) {
  return 1.0f - 2.0f * frcp(1.0f + __builtin_amdgcn_exp2f(x * (2.0f * LOG2E)));
}

// XLA ErfInv32 (Giles polynomial), log via hw
__device__ __forceinline__ float erfinv_f(float x) {
  float w = -flog(fmaf(-x, x, 1.0f));
  float p;
  if (w < 5.0f) {
    w = w - 2.5f;
    p = 2.81022636e-08f;
    p = 3.43273939e-07f + p * w;
    p = -3.5233877e-06f + p * w;
    p = -4.39150654e-06f + p * w;
    p = 0.00021858087f  + p * w;
    p = -0.00125372503f + p * w;
    p = -0.00417768164f + p * w;
    p = 0.246640727f    + p * w;
    p = 1.50140941f     + p * w;
  } else {
    w = sqrtf(w) - 3.0f;
    p = -0.000200214257f;
    p = 0.000100950558f + p * w;
    p = 0.00134934322f  + p * w;
    p = -0.00367342844f + p * w;
    p = 0.00573950773f  + p * w;
    p = -0.0076224613f  + p * w;
    p = 0.00943887047f  + p * w;
    p = 1.00167406f     + p * w;
    p = 2.83297682f     + p * w;
  }
  return p * x;
}

// round-to-nearest-even f32 -> bf16 bits
__device__ __forceinline__ uint32_t bf16rne(float f) {
  uint32_t u = __float_as_uint(f);
  return (u + 0x7fffu + ((u >> 16) & 1u)) >> 16;
}

// ======== prep_misc: register-LIGHT 256-thread blocks, inputs-only ========
// [0,2000)       RNG G/ZM/ZO: 4 elems/thread, float4 stores (2,048,000 = 2000x256x4)
// [2000,3024)    WSUM
// [3024,3028)    tsc cumulative
// [3028,3108)    WTB bf16 swizzled
// [3108]         bias
// [3109,3113)    M + zc-global (T1/eb2 local)
#define RB_RNG   0
#define RB_WSUM  2000
#define RB_TSC   3024
#define RB_WTB   3028
#define RB_BIAS  3108
#define RB_MZC   3109
#define RB_TOT   3113
__global__ __launch_bounds__(256) void prep_misc(
    const float* __restrict__ Wk, const float* __restrict__ Wr,
    const float* __restrict__ We1, const float* __restrict__ be1,
    const float* __restrict__ We2, const float* __restrict__ be2,
    const float* __restrict__ Wm, const float* __restrict__ bm,
    const float* __restrict__ Wy, const float* __restrict__ by,
    const float* __restrict__ Wf, const float* __restrict__ bf,
    const float* __restrict__ Wfa, const float* __restrict__ bfa,
    const float* __restrict__ bl, float* __restrict__ ws) {
  __shared__ float smem[768];           // MZC: T1(640)+eb2(128)
  const int bid = blockIdx.x, tid = threadIdx.x;

  if (bid < RB_WSUM) {
    // 4 consecutive elements per thread; region boundaries are 4-aligned,
    // so each 4-group lies entirely in one region. Values bit-identical to R22.
    const int base = (bid * 256 + tid) * 4;
    const int NG = 4 * TT * BN * KK;          // 1,638,400
    float v[4];
    if (base < NG) {
#pragma unroll
      for (int j = 0; j < 4; ++j) {
        const int id = base + j;
        const int t = id / (BN * 4 * KK);
        const int r1 = id % (BN * 4 * KK);
        const int row = r1 / (4 * KK);
        const int r2 = r1 % (4 * KK);
        const int head = r2 / KK, k = r2 % KK;
        const uint32_t k0 = KT.v[t * 16 + head * 4 + 0];
        const uint32_t k1 = KT.v[t * 16 + head * 4 + 1];
        float u = u01f(pbits(k0, k1, (uint32_t)(row * KK + k)));
        u = fmaxf(TINYF, u * (1.0f - TINYF) + TINYF);
        v[j] = -flog(-flog(u));
      }
      *(float4*)&ws[WS_G + base] = make_float4(v[0], v[1], v[2], v[3]);
    } else if (base < NG + TT * BN * 2) {
      const int jj0 = base - NG;
#pragma unroll
      for (int j = 0; j < 4; ++j) {
        const int jj = jj0 + j;
        const int t = jj / (BN * 2);
        const uint32_t n = (uint32_t)(jj % (BN * 2));
        const uint32_t k0 = KT.v[t * 16 + 2], k1 = KT.v[t * 16 + 3];
        float u = u01f(pbits(k0, k1, n)) * 2.0f - LO_N;
        u = fmaxf(-LO_N, u);
        v[j] = 1.41421356f * erfinv_f(u);
      }
      *(float4*)&ws[WS_ZM + jj0] = make_float4(v[0], v[1], v[2], v[3]);
    } else {
      const int jj0 = base - NG - TT * BN * 2;
#pragma unroll
      for (int j = 0; j < 4; ++j) {
        const int jj = jj0 + j;
        const int t = jj / (BN * 3);
        const int r2 = jj % (BN * 3);
        const int row = r2 / 3, hh = r2 % 3;
        const uint32_t k0 = KT.v[t * 16 + (hh + 1) * 4 + 2];
        const uint32_t k1 = KT.v[t * 16 + (hh + 1) * 4 + 3];
        float u = u01f(pbits(k0, k1, (uint32_t)row)) * 2.0f - LO_N;
        u = fmaxf(-LO_N, u);
        v[j] = 1.41421356f * erfinv_f(u);
      }
      *(float4*)&ws[WS_ZO + jj0] = make_float4(v[0], v[1], v[2], v[3]);
    }
  } else if (bid < RB_TSC) {
    const int idx = (bid - RB_WSUM) * 256 + tid;    // < 262144
    const int q = idx >> 10, col = idx & 1023;
    ws[WS_WSUM + idx] = Wk[(size_t)(EE + q) * 1024 + col] + Wr[(size_t)q * 1024 + col];
  } else if (bid < RB_WTB) {
    const int col = (bid - RB_TSC) * 256 + tid;
    float s = 0.0f;
    for (int p = 0; p < TT; ++p) {
      s += Wk[(size_t)(EE + HH + p) * 1024 + col];
      ws[WS_TSC + p * 1024 + col] = s;
    }
  } else if (bid < RB_BIAS) {
    const int idx = (bid - RB_WTB) * 256 + tid;   // < 20480
    const int o = idx >> 8, q = idx & 255;
    float v = 0.0f;
    if (o < 30)      v = Wm[q * 30 + o];
    else if (o < 45) v = Wy[q * 15 + (o - 30)];
    else if (o < 60) v = Wf[q * 15 + (o - 45)];
    else if (o < 75) v = Wfa[q * 15 + (o - 60)];
    uint16_t* wtb = (uint16_t*)&ws[WS_WTB];
    wtb[o * 256 + (q ^ ((o & 7) << 3))] = (uint16_t)bf16rne(v);
  } else if (bid == RB_BIAS) {
    if (tid < 80) {
      float v = 0.0f;
      if (tid < 30)      v = bm[tid];
      else if (tid < 45) v = by[tid - 30];
      else if (tid < 60) v = bf[tid - 45];
      else if (tid < 75) v = bfa[tid - 60];
      ws[WS_BIAS + tid] = v;
    }
  } else {
    // M = (We1@We2)@Wk1; zc-global = (be1@We2+be2)@Wk1 + bl (T1/eb2 local)
    float* T1s = smem;                // 5*128
    float* eb2s = smem + 640;         // 128
    if (tid < EE) {
      const int q = tid;
      float t0 = 0.f, t1 = 0.f, t2 = 0.f, t3 = 0.f, t4 = 0.f;
      float eb = be2[q];
      for (int e = 0; e < EE; ++e) {
        const float w2 = We2[e * EE + q];
        t0 = fmaf(We1[0 * EE + e], w2, t0);
        t1 = fmaf(We1[1 * EE + e], w2, t1);
        t2 = fmaf(We1[2 * EE + e], w2, t2);
        t3 = fmaf(We1[3 * EE + e], w2, t3);
        t4 = fmaf(We1[4 * EE + e], w2, t4);
        eb = fmaf(be1[e], w2, eb);
      }
      T1s[0 * 128 + q] = t0; T1s[1 * 128 + q] = t1; T1s[2 * 128 + q] = t2;
      T1s[3 * 128 + q] = t3; T1s[4 * 128 + q] = t4; eb2s[q] = eb;
    }
    __syncthreads();
    const int col = (bid - RB_MZC) * 256 + tid;   // 0..1023
    float m0 = 0.f, m1 = 0.f, m2 = 0.f, m3 = 0.f, m4 = 0.f;
    float zacc = bl[col];
    for (int q = 0; q < EE; ++q) {
      const float wv = Wk[(size_t)q * 1024 + col];
      m0 = fmaf(T1s[0 * 128 + q], wv, m0);
      m1 = fmaf(T1s[1 * 128 + q], wv, m1);
      m2 = fmaf(T1s[2 * 128 + q], wv, m2);
      m3 = fmaf(T1s[3 * 128 + q], wv, m3);
      m4 = fmaf(T1s[4 * 128 + q], wv, m4);
      zacc = fmaf(eb2s[q], wv, zacc);
    }
    ws[WS_M + 0 * 1024 + col] = m0;
    ws[WS_M + 1 * 1024 + col] = m1;
    ws[WS_M + 2 * 1024 + col] = m2;
    ws[WS_M + 3 * 1024 + col] = m3;
    ws[WS_M + 4 * 1024 + col] = m4;
    ws[WS_ZC + col] = zacc;
  }
}

// ===== prep_czgemm: CZ = H @ WSUM + zc via MFMA (launched AFTER prep_misc) =====
// 128x128 tile/block, K=256 staged once; grid (4096/128)x(1024/128) = 256 blocks.
__global__ __launch_bounds__(512) void prep_czgemm(
    const float* __restrict__ state_h, float* __restrict__ ws) {
  __shared__ short Ab[128 * 256];   // h bf16, [m][k^((m&7)<<3)]   64 KB
  __shared__ short Bb[128 * 256];   // wsum bf16, [n][k^((n&7)<<3)] 64 KB
  const int tid = threadIdx.x;
  const int brow = blockIdx.x >> 3, bcol = blockIdx.x & 7;
  const int row0 = brow * 128, col0 = bcol * 128;

  for (int i = tid; i < 128 * 256; i += 512) {
    const int m = i >> 8, k = i & 255;
    Ab[m * 256 + (k ^ ((m & 7) << 3))] =
        (short)bf16rne(state_h[(size_t)(row0 + m) * HH + k]);
  }
  for (int i = tid; i < 128 * 256; i += 512) {
    const int k = i >> 7, n = i & 127;   // coalesced WSUM row reads
    Bb[n * 256 + (k ^ ((n & 7) << 3))] =
        (short)bf16rne(ws[WS_WSUM + k * 1024 + col0 + n]);
  }
  __syncthreads();

  const int wv = tid >> 6, lane = tid & 63;
  const int wr = wv >> 2, wc = wv & 3;    // wave tile: rows wr*64+, cols wc*32+
  const int rc = lane & 15, hq = lane >> 4;
  f32x4 acc[4][2];
#pragma unroll
  for (int fr = 0; fr < 4; ++fr)
#pragma unroll
    for (int fc = 0; fc < 2; ++fc) acc[fr][fc] = (f32x4){0.f, 0.f, 0.f, 0.f};

#pragma unroll
  for (int kk = 0; kk < 8; ++kk) {
    const int kbase = kk * 32 + hq * 8;
    short8v av[4], bv[2];
#pragma unroll
    for (int fr = 0; fr < 4; ++fr) {
      const int m = wr * 64 + fr * 16 + rc;
      av[fr] = *(const short8v*)&Ab[m * 256 + (kbase ^ ((m & 7) << 3))];
    }
#pragma unroll
    for (int fc = 0; fc < 2; ++fc) {
      const int n = wc * 32 + fc * 16 + rc;
      bv[fc] = *(const short8v*)&Bb[n * 256 + (kbase ^ ((n & 7) << 3))];
    }
#pragma unroll
    for (int fr = 0; fr < 4; ++fr)
#pragma unroll
      for (int fc = 0; fc < 2; ++fc)
        acc[fr][fc] = __builtin_amdgcn_mfma_f32_16x16x32_bf16(av[fr], bv[fc],
                                                              acc[fr][fc], 0, 0, 0);
  }

#pragma unroll
  for (int fc = 0; fc < 2; ++fc) {
    const int colg = col0 + wc * 32 + fc * 16 + rc;
    const float zcv = ws[WS_ZC + colg];
#pragma unroll
    for (int fr = 0; fr < 4; ++fr) {
#pragma unroll
      for (int j = 0; j < 4; ++j) {
        const int row = row0 + wr * 64 + fr * 16 + hq * 4 + j;
        ws[WS_CZ + (size_t)row * 1024 + colg] = acc[fr][fc][j] + zcv;
      }
    }
  }
}

// ---------------- main: 8 rows/block, 512 blocks, 20 steps ----------------
__global__ __launch_bounds__(512) void decode_main(
    const float* __restrict__ conditions, const float* __restrict__ state_h,
    const float* __restrict__ state_c, const float* __restrict__ ws,
    float* __restrict__ out, int use_cz) {
  __shared__ float Msh[5 * 1024];       // 20 KB
  __shared__ short WTBs[80 * 256];      // 40 KB bf16 swizzled weights
  __shared__ short hb[16 * 256];        // 8 KB bf16 swizzled h (rows 8..15 zero)
  __shared__ float psh[8 * PSTR];       // head outputs (pre-biased)
  __shared__ float biasL[80];
  __shared__ float conds[8 * 8];

  const int tid = threadIdx.x;
  const int row0 = blockIdx.x * 8;
  const int u = tid & 255;
  const int half = tid >> 8;
  const int rbase = half * 4;

  for (int i = tid; i < 5 * 1024; i += 512) Msh[i] = ws[WS_M + i];
  if (tid < 80) biasL[tid] = ws[WS_BIAS + tid];
  if (tid < 8 * NCOND) {
    const int r = tid / NCOND, c = tid - r * NCOND;
    conds[r * 8 + c] = conditions[(size_t)(row0 + r) * (TT * NCOND) + c];  // [:,0,:]
  }
  float sc[4];
#pragma unroll
  for (int rr = 0; rr < 4; ++rr) sc[rr] = state_c[(size_t)(row0 + rbase + rr) * HH + u];

  // Phase-C role constants (t-invariant)
  const bool cth = (tid < 256);
  const int kci = tid & 7;
  const int rci = tid >> 5;
  const int headci = (tid >> 3) & 3;
  const int crow = row0 + rci;
  const int cbase2 = headci ? (30 + 15 * (headci - 1)) : 0;

  float cz[4][4];
  if (use_cz) {
#pragma unroll
    for (int g = 0; g < 4; ++g)
#pragma unroll
      for (int rr = 0; rr < 4; ++rr)
        cz[g][rr] = ws[WS_CZ + (size_t)(row0 + rbase + rr) * 1024 + g * 256 + u];
    {
      uint32_t* dst = (uint32_t*)WTBs;
      const uint32_t* src = (const uint32_t*)&ws[WS_WTB];
      for (int i = tid; i < 80 * 128; i += 512) dst[i] = src[i];
      uint32_t* hz = (uint32_t*)hb;
      for (int i = tid; i < 1024; i += 512) hz[1024 + i] = 0u;   // rows 8..15 ONLY
    }
    __syncthreads();
  } else {
    float* hstage = (float*)WTBs;
    for (int i = tid; i < 8 * HH; i += 512) hstage[i] = state_h[(size_t)row0 * HH + i];
    __syncthreads();
#pragma unroll
    for (int g = 0; g < 4; ++g) {
      const float z = ws[WS_ZC + g * 256 + u];
#pragma unroll
      for (int rr = 0; rr < 4; ++rr) cz[g][rr] = z;
    }
    for (int q = 0; q < HH; ++q) {
      const float w0 = ws[WS_WSUM + q * 1024 + u];
      const float w1 = ws[WS_WSUM + q * 1024 + 256 + u];
      const float w2 = ws[WS_WSUM + q * 1024 + 512 + u];
      const float w3 = ws[WS_WSUM + q * 1024 + 768 + u];
#pragma unroll
      for (int rr = 0; rr < 4; ++rr) {
        const float e = hstage[(rbase + rr) * HH + q];
        cz[0][rr] = fmaf(e, w0, cz[0][rr]);
        cz[1][rr] = fmaf(e, w1, cz[1][rr]);
        cz[2][rr] = fmaf(e, w2, cz[2][rr]);
        cz[3][rr] = fmaf(e, w3, cz[3][rr]);
      }
    }
    __syncthreads();
    {
      uint32_t* dst = (uint32_t*)WTBs;
      const uint32_t* src = (const uint32_t*)&ws[WS_WTB];
      for (int i = tid; i < 80 * 128; i += 512) dst[i] = src[i];
      uint32_t* hz = (uint32_t*)hb;
      for (int i = tid; i < 1024; i += 512) hz[1024 + i] = 0u;
    }
    __syncthreads();
  }

  for (int t = 0; t < TT; ++t) {
    // ---- prefetch step-t RNG draws into registers (hides cold-HBM under A/B) ----
    float pg = 0.0f, pz0 = 0.0f, pz1 = 0.0f, pzz = 0.0f;
    if (cth) {
      if (kci < 5)
        pg = ws[WS_G + (((size_t)t * BN + crow) * 4 + headci) * KK + kci];
      if (kci == 0) {
        if (headci == 0) {
          pz0 = ws[WS_ZM + ((size_t)t * BN + crow) * 2 + 0];
          pz1 = ws[WS_ZM + ((size_t)t * BN + crow) * 2 + 1];
        } else {
          pzz = ws[WS_ZO + ((size_t)t * BN + crow) * 3 + (headci - 1)];
        }
      }
    }
    // ---- Phase A ----
    {
      const float ts0 = ws[WS_TSC + t * 1024 + u];
      const float ts1 = ws[WS_TSC + t * 1024 + 256 + u];
      const float ts2 = ws[WS_TSC + t * 1024 + 512 + u];
      const float ts3 = ws[WS_TSC + t * 1024 + 768 + u];
      float mA[5], mB[5], mC[5], mD[5];
#pragma unroll
      for (int c = 0; c < 5; ++c) {
        mA[c] = Msh[c * 1024 + u];
        mB[c] = Msh[c * 1024 + 256 + u];
        mC[c] = Msh[c * 1024 + 512 + u];
        mD[c] = Msh[c * 1024 + 768 + u];
      }
#pragma unroll
      for (int rr = 0; rr < 4; ++rr) {
        const int row = rbase + rr;
        const float c0 = conds[row * 8 + 0], c1 = conds[row * 8 + 1], c2 = conds[row * 8 + 2],
                    c3 = conds[row * 8 + 3], c4 = conds[row * 8 + 4];
        float zi = cz[0][rr] + ts0, zf = cz[1][rr] + ts1,
              zg = cz[2][rr] + ts2, zo = cz[3][rr] + ts3;
        zi = fmaf(c0, mA[0], zi); zi = fmaf(c1, mA[1], zi); zi = fmaf(c2, mA[2], zi);
        zi = fmaf(c3, mA[3], zi); zi = fmaf(c4, mA[4], zi);
        zf = fmaf(c0, mB[0], zf); zf = fmaf(c1, mB[1], zf); zf = fmaf(c2, mB[2], zf);
        zf = fmaf(c3, mB[3], zf); zf = fmaf(c4, mB[4], zf);
        zg = fmaf(c0, mC[0], zg); zg = fmaf(c1, mC[1], zg); zg = fmaf(c2, mC[2], zg);
        zg = fmaf(c3, mC[3], zg); zg = fmaf(c4, mC[4], zg);
        zo = fmaf(c0, mD[0], zo); zo = fmaf(c1, mD[1], zo); zo = fmaf(c2, mD[2], zo);
        zo = fmaf(c3, mD[3], zo); zo = fmaf(c4, mD[4], zo);
        const float cv = fsig(zf) * sc[rr] + fsig(zi) * ftanh(zg);
        const float hv = fsig(zo) * ftanh(cv);
        hb[row * 256 + (u ^ ((row & 7) << 3))] = (short)bf16rne(hv);
      }
    }
    __syncthreads();
    // ---- Phase B: MFMA heads ----
    {
      const int wv = tid >> 6;
      if (wv < 5) {
        const int lane = tid & 63;
        const int rc = lane & 15;
        const int hq = lane >> 4;
        const int nn = wv * 16 + rc;
        const int aswz = (rc & 7) << 3;
        const int bswz = (nn & 7) << 3;
        f32x4 acc = {0.0f, 0.0f, 0.0f, 0.0f};
#pragma unroll
        for (int kk = 0; kk < 8; ++kk) {
          const int kbase = kk * 32 + hq * 8;
          const short8v av = *(const short8v*)&hb[rc * 256 + (kbase ^ aswz)];
          const short8v bv = *(const short8v*)&WTBs[nn * 256 + (kbase ^ bswz)];
          acc = __builtin_amdgcn_mfma_f32_16x16x32_bf16(av, bv, acc, 0, 0, 0);
        }
        if (hq < 2) {
#pragma unroll
          for (int j = 0; j < 4; ++j) {
            const int prow = hq * 4 + j;
            psh[prow * PSTR + nn] = acc[j] + biasL[nn];
          }
        }
      }
    }
    __syncthreads();
    // ---- Phase C: wave-parallel sampling (prefetched RNG) ----
    if (cth) {
      const float lk = (kci < 5) ? psh[rci * PSTR + cbase2 + kci] : -INFINITY;
      float mx = fmaxf(lk, __shfl_xor(lk, 1));
      mx = fmaxf(mx, __shfl_xor(mx, 2));
      mx = fmaxf(mx, __shfl_xor(mx, 4));
      const float ek = (kci < 5) ? fexp(lk - mx) : 0.0f;
      float ss = ek + __shfl_xor(ek, 1);
      ss += __shfl_xor(ss, 2);
      ss += __shfl_xor(ss, 4);
      const float rss = frcp(ss);
      float v = -INFINITY;
      if (kci < 5) v = lk + pg;
      float vm = fmaxf(v, __shfl_xor(v, 1));
      vm = fmaxf(vm, __shfl_xor(vm, 2));
      vm = fmaxf(vm, __shfl_xor(vm, 4));
      int cand = (v == vm) ? kci : 8;
      cand = min(cand, __shfl_xor(cand, 1));
      cand = min(cand, __shfl_xor(cand, 2));
      cand = min(cand, __shfl_xor(cand, 4));
      const int idx = cand;
      const size_t ob = headci
          ? ((size_t)BN * TT * 30 + (size_t)(headci - 1) * BN * TT * 15 +
             ((size_t)crow * TT + t) * 15)
          : ((size_t)crow * TT + t) * 30;
      if (kci < 5) {
        out[ob + kci] = ek * rss;
        out[ob + 5 + kci] = psh[rci * PSTR + cbase2 + 5 + kci];
        out[ob + 10 + kci] = fexp(psh[rci * PSTR + cbase2 + 10 + kci]);
        if (headci == 0) {
          out[ob + 15 + kci] = psh[rci * PSTR + 15 + kci];
          out[ob + 20 + kci] = fexp(psh[rci * PSTR + 20 + kci]);
          out[ob + 25 + kci] = ftanh(psh[rci * PSTR + 25 + kci]);
        }
      }
      if (kci == 0) {
        if (headci == 0) {
          const float mu = psh[rci * PSTR + 5 + idx];
          const float sl = fexp(psh[rci * PSTR + 10 + idx]);
          const float mula = psh[rci * PSTR + 15 + idx];
          const float sla = fexp(psh[rci * PSTR + 20 + idx]);
          const float rho = ftanh(psh[rci * PSTR + 25 + idx]);
          conds[rci * 8 + 0] = mu + sl * pz0;
          conds[rci * 8 + 1] = mula + sla * (rho * pz0 + sqrtf(1.0f - rho * rho) * pz1);
        } else {
          conds[rci * 8 + 1 + headci] =
              psh[rci * PSTR + cbase2 + 5 + idx] +
              fexp(psh[rci * PSTR + cbase2 + 10 + idx]) * pzz;
        }
      }
    }
    __syncthreads();
  }
}

extern "C" void kernel_launch(void* const* d_in, const int* in_sizes, int n_in,
                              void* d_out, int out_size, void* d_ws, size_t ws_size,
                              hipStream_t stream) {
  const float* conditions = (const float*)d_in[0];
  const float* state_h = (const float*)d_in[1];
  const float* state_c = (const float*)d_in[2];
  // d_in[3] = steps_n (=20, compile-time TT)
  const float* We1 = (const float*)d_in[4];
  const float* be1 = (const float*)d_in[5];
  const float* We2 = (const float*)d_in[6];
  const float* be2 = (const float*)d_in[7];
  const float* Wk  = (const float*)d_in[8];
  const float* Wr  = (const float*)d_in[9];
  const float* bl  = (const float*)d_in[10];
  const float* Wm  = (const float*)d_in[11];
  const float* bm  = (const float*)d_in[12];
  const float* Wy  = (const float*)d_in[13];
  const float* by  = (const float*)d_in[14];
  const float* Wf  = (const float*)d_in[15];
  const float* bf  = (const float*)d_in[16];
  const float* Wfa = (const float*)d_in[17];
  const float* bfa = (const float*)d_in[18];
  float* ws = (float*)d_ws;
  float* out = (float*)d_out;

  const int use_cz = (ws_size >= (size_t)WS_END * 4) ? 1 : 0;

  prep_misc<<<dim3(RB_TOT), dim3(256), 0, stream>>>(
      Wk, Wr, We1, be1, We2, be2, Wm, bm, Wy, by, Wf, bf, Wfa, bfa, bl, ws);
  if (use_cz) {
    prep_czgemm<<<dim3(256), dim3(512), 0, stream>>>(state_h, ws);
  }
  decode_main<<<dim3(BN / 8), dim3(512), 0, stream>>>(
      conditions, state_h, state_c, ws, out, use_cz);
}